// Round 13
// baseline (250.646 us; speedup 1.0000x reference)
//
#include <hip/hip_runtime.h>
#include <hip/hip_bf16.h>

typedef __attribute__((ext_vector_type(8))) short short8;
typedef __attribute__((ext_vector_type(4))) short s16x4;
typedef __attribute__((ext_vector_type(4))) float f32x4;

typedef const __attribute__((address_space(1))) unsigned* gp1;
typedef __attribute__((address_space(3))) unsigned* lp3;

__device__ inline short f2bf(float f) {
    union { float f; unsigned u; } v; v.f = f;
    unsigned r = v.u + 0x7fffu + ((v.u >> 16) & 1u);
    return (short)(r >> 16);
}

// ---------------------------------------------------------------------------
// P0: fp32 -> bf16 flat convert (x)
// ---------------------------------------------------------------------------
__global__ __launch_bounds__(256) void cvt_bf16(
    const float* __restrict__ src, short* __restrict__ dst, int n4)
{
    int i = blockIdx.x * 256 + threadIdx.x;
    if (i < n4) {
        float4 v = ((const float4*)src)[i];
        s16x4 o = { f2bf(v.x), f2bf(v.y), f2bf(v.z), f2bf(v.w) };
        ((s16x4*)dst)[i] = o;
    }
}

// ---------------------------------------------------------------------------
// P1: W[K][N] fp32 -> W^T[N][K] bf16 (64x64 LDS tile transpose)
// ---------------------------------------------------------------------------
__global__ __launch_bounds__(256) void tr_w(
    const float* __restrict__ src, short* __restrict__ dst, int K, int N)
{
    __shared__ float t[64][65];
    const int k0 = blockIdx.x * 64, n0 = blockIdx.y * 64;
    const int r = threadIdx.x >> 4, c4 = (threadIdx.x & 15) * 4;
#pragma unroll
    for (int j = 0; j < 4; j++) {
        float4 v = *(const float4*)(src + (size_t)(k0 + r + 16 * j) * N + n0 + c4);
        t[r + 16 * j][c4 + 0] = v.x; t[r + 16 * j][c4 + 1] = v.y;
        t[r + 16 * j][c4 + 2] = v.z; t[r + 16 * j][c4 + 3] = v.w;
    }
    __syncthreads();
#pragma unroll
    for (int j = 0; j < 4; j++) {
        const int n = r + 16 * j;
        s16x4 o = { f2bf(t[c4 + 0][n]), f2bf(t[c4 + 1][n]),
                    f2bf(t[c4 + 2][n]), f2bf(t[c4 + 3][n]) };
        *(s16x4*)(dst + (size_t)(n0 + n) * K + k0 + c4) = o;
    }
}

// ---------------------------------------------------------------------------
// K1: qkv = xb @ WqT^T  (M=8192, K=512, N=1536). R9 128x64 tiles (frozen).
// ---------------------------------------------------------------------------
__global__ __launch_bounds__(256) void qkv_gemm(
    const short* __restrict__ A, const short* __restrict__ BT,
    short* __restrict__ q, short* __restrict__ k, short* __restrict__ vt)
{
    __shared__ short sA[128][32];   // NO padding: global_load_lds needs dense
    __shared__ short sB[64][32];

    const int tid  = threadIdx.x;
    const int wv   = tid >> 6, lane = tid & 63;
    const int quad = lane >> 4, l16 = lane & 15;
    const int m0 = blockIdx.x * 128, n0 = blockIdx.y * 64;

    f32x4 acc[2][4];
#pragma unroll
    for (int i = 0; i < 2; i++)
#pragma unroll
        for (int j = 0; j < 4; j++) acc[i][j] = (f32x4){0.f, 0.f, 0.f, 0.f};

    const short* a_src = A  + (size_t)(m0 + wv * 32 + (lane >> 2)) * 512 + (lane & 3) * 8;
    const short* b_src = BT + (size_t)(n0 + wv * 16 + (lane >> 2)) * 512 + (lane & 3) * 8;
    char* a_dst = (char*)sA + wv * 2048;
    char* b_dst = (char*)sB + wv * 1024;

    for (int ks = 0; ks < 16; ks++) {
        __syncthreads();
        const short* ap = a_src + ks * 32;
        const short* bp = b_src + ks * 32;
        __builtin_amdgcn_global_load_lds((gp1)(ap),            (lp3)(a_dst),        16, 0, 0);
        __builtin_amdgcn_global_load_lds((gp1)(ap + 16 * 512), (lp3)(a_dst + 1024), 16, 0, 0);
        __builtin_amdgcn_global_load_lds((gp1)(bp),            (lp3)(b_dst),        16, 0, 0);
        __syncthreads();

        short8 af[2], bf[4];
#pragma unroll
        for (int f = 0; f < 2; f++)
            af[f] = *(const short8*)&sA[wv * 32 + f * 16 + l16][quad * 8];
#pragma unroll
        for (int f = 0; f < 4; f++)
            bf[f] = *(const short8*)&sB[f * 16 + l16][quad * 8];
#pragma unroll
        for (int fm = 0; fm < 2; fm++)
#pragma unroll
            for (int fn = 0; fn < 4; fn++)
                acc[fm][fn] = __builtin_amdgcn_mfma_f32_16x16x32_bf16(
                    af[fm], bf[fn], acc[fm][fn], 0, 0, 0);
    }

    const int sec = n0 >> 9;   // 0=q 1=k 2=v
#pragma unroll
    for (int fn = 0; fn < 4; fn++) {
        const int gc = n0 + fn * 16 + l16;
        const int cc = gc & 511;
        const int h = cc >> 6, d = cc & 63;
#pragma unroll
        for (int fm = 0; fm < 2; fm++)
#pragma unroll
            for (int i = 0; i < 4; i++) {
                const int gm = m0 + wv * 32 + fm * 16 + quad * 4 + i;
                const int b = gm >> 10, n = gm & 1023;
                const int bh = b * 8 + h;
                if (sec == 0)      q[((size_t)(bh * 1024 + n)) * 64 + d] = f2bf(acc[fm][fn][i] * 0.125f);
                else if (sec == 1) k[((size_t)(bh * 1024 + n)) * 64 + d] = f2bf(acc[fm][fn][i]);
                else               vt[((size_t)(bh * 64 + d)) * 1024 + n] = f2bf(acc[fm][fn][i]);
            }
    }
}

// ---------------------------------------------------------------------------
// K2: attention (R13): KEY-SPLIT ACROSS WAVES for 2x TLP at fixed work.
//   R11 (2blk x 4w) and R12 (1blk x 8w) both = 8 waves/CU = 102us with all
//   pipes <25% => TLP-starved; work/CU fixed at 16 q-tiles, so more waves
//   requires splitting keys. Fixed-Mhat softmax (R8) makes key-split EXACTLY
//   additive: shared per-row bound => partial ls and O just sum.
//   Block = (bh, 64 q-rows), 512 thr / 8 waves = 4 q-tiles x 2 key-halves;
//   each wave: 16 rows x 512 keys (8 chunks). Grid (16,64)=1024 blocks;
//   LDS 73.5KB -> 2 blocks/CU -> 16 waves/CU (2x R12).
//   Staging: sK[2]/sV[2]; thread (tid>>8) fills buffer hs, wave (w>>2) reads
//   buffer hf. Sweep A: norms -> block-reduce over halves -> ratio/Mhat.
//   Sweep B: QK+exp+PV per half; combine ls via lsred, O via sO roundtrip.
//   (512,2): VGPR cap 256, est ~100. TRIPWIRE: WRITE_SIZE ~8.2MB.
// ---------------------------------------------------------------------------
__global__ __launch_bounds__(512, 2) void attn_k(
    const short* __restrict__ q, const short* __restrict__ kk,
    const short* __restrict__ vt, const float* __restrict__ spd,
    const float* __restrict__ hm, short* __restrict__ o)
{
    __shared__ short sK[2][64][72];
    __shared__ short sV[2][64][72];
    __shared__ short sP[8][16][72];
    __shared__ float sO[4][16][68];
    __shared__ float nred[4][2][4][16];
    __shared__ float lsred[2][4][16];

    const int tid  = threadIdx.x;
    const int w    = tid >> 6, lane = tid & 63;
    const int quad = lane >> 4, l16 = lane & 15;
    const int t    = w & 3;          // q-tile of this wave
    const int hf   = w >> 2;         // key-half of this wave
    const int qt = blockIdx.x, bh = blockIdx.y;
    const int b = bh >> 3, h = bh & 7;
    const int q0 = qt * 64;

    // Q as B-operand for tile t: lane l16 = q-col, quad*8 = d
    const short* qb = q + ((size_t)bh * 1024 + q0 + t * 16 + l16) * 64;
    short8 aq0 = *(const short8*)(qb + quad * 8);
    short8 aq1 = *(const short8*)(qb + 32 + quad * 8);

    // staging map: thread fills buffer hs with chunk (hs*8 + c)
    const int hs = tid >> 8;         // 0/1
    const int tt = tid & 255;
    const int sr = tt & 31, sc = (tt >> 5) * 8;
    const short* ksrc = kk + (size_t)bh * 65536 + (size_t)(hs * 512 + sr) * 64 + sc;
    const short* vsrc = vt + (size_t)bh * 65536 + (size_t)sr * 1024 + hs * 512 + sc;
    // spd for this wave's rows and key-half
    const float* sp = spd + ((size_t)b * 1024 + q0 + t * 16 + l16) * 1024 + hf * 512 + quad * 4;

    // ===== sweep A: row norms + max bound over this wave's key-half ======
    float dn = 0.f, pn = 0.f, mxs = -1e30f, mxp = -1e30f;
    short8 k0 = *(const short8*)(ksrc);
    short8 k1 = *(const short8*)(ksrc + 2048);

    for (int c = 0; c < 8; ++c) {
        __syncthreads();
        *(short8*)&sK[hs][sr][sc]      = k0;
        *(short8*)&sK[hs][sr + 32][sc] = k1;
        __syncthreads();
        if (c < 7) {
            k0 = *(const short8*)(ksrc + (c + 1) * 4096);
            k1 = *(const short8*)(ksrc + (c + 1) * 4096 + 2048);
        }
        float4 sv0 = *(const float4*)(sp + c * 64 +  0);
        float4 sv1 = *(const float4*)(sp + c * 64 + 16);
        float4 sv2 = *(const float4*)(sp + c * 64 + 32);
        float4 sv3 = *(const float4*)(sp + c * 64 + 48);
        f32x4 a[4];
#pragma unroll
        for (int tk = 0; tk < 4; tk++) {
            a[tk] = (f32x4){0.f, 0.f, 0.f, 0.f};
            a[tk] = __builtin_amdgcn_mfma_f32_16x16x32_bf16(
                *(const short8*)&sK[hf][tk * 16 + l16][quad * 8], aq0, a[tk], 0, 0, 0);
            a[tk] = __builtin_amdgcn_mfma_f32_16x16x32_bf16(
                *(const short8*)&sK[hf][tk * 16 + l16][32 + quad * 8], aq1, a[tk], 0, 0, 0);
        }
        const float4 svv[4] = {sv0, sv1, sv2, sv3};
#pragma unroll
        for (int tk = 0; tk < 4; tk++)
#pragma unroll
            for (int i = 0; i < 4; i++) {
                float s  = a[tk][i];
                float sv = ((const float*)&svv[tk])[i];
                float ps = s * sv;
                dn = fmaf(s, s, dn);
                pn = fmaf(ps, ps, pn);
                mxs = fmaxf(mxs, s);
                mxp = fmaxf(mxp, ps);
            }
    }
    dn += __shfl_xor(dn, 16, 64); dn += __shfl_xor(dn, 32, 64);
    pn += __shfl_xor(pn, 16, 64); pn += __shfl_xor(pn, 32, 64);
    mxs = fmaxf(mxs, __shfl_xor(mxs, 16, 64)); mxs = fmaxf(mxs, __shfl_xor(mxs, 32, 64));
    mxp = fmaxf(mxp, __shfl_xor(mxp, 16, 64)); mxp = fmaxf(mxp, __shfl_xor(mxp, 32, 64));
    if (quad == 0) {
        nred[0][hf][t][l16] = dn;  nred[1][hf][t][l16] = pn;
        nred[2][hf][t][l16] = mxs; nred[3][hf][t][l16] = mxp;
    }
    __syncthreads();
    const float dnT  = nred[0][0][t][l16] + nred[0][1][t][l16];
    const float pnT  = nred[1][0][t][l16] + nred[1][1][t][l16];
    const float mxsT = fmaxf(nred[2][0][t][l16], nred[2][1][t][l16]);
    const float mxpT = fmaxf(nred[3][0][t][l16], nred[3][1][t][l16]);
    const float ratio = sqrtf(dnT) / fmaxf(sqrtf(pnT), 1e-12f);  // per q-row l16
    const float Mhat  = mxsT + ratio * mxpT;                     // >= max over ALL keys

    // ===== sweep B: QK + fixed-max exp + PV over this wave's half ========
    float ls = 0.f;
    f32x4 O[4];
#pragma unroll
    for (int dt = 0; dt < 4; dt++) O[dt] = (f32x4){0.f, 0.f, 0.f, 0.f};

    k0 = *(const short8*)(ksrc);
    k1 = *(const short8*)(ksrc + 2048);
    short8 v0 = *(const short8*)(vsrc);
    short8 v1 = *(const short8*)(vsrc + 32768);

    for (int c = 0; c < 8; ++c) {
        __syncthreads();
        *(short8*)&sK[hs][sr][sc]      = k0;
        *(short8*)&sK[hs][sr + 32][sc] = k1;
        *(short8*)&sV[hs][sr][sc]      = v0;
        *(short8*)&sV[hs][sr + 32][sc] = v1;
        __syncthreads();
        if (c < 7) {
            k0 = *(const short8*)(ksrc + (c + 1) * 4096);
            k1 = *(const short8*)(ksrc + (c + 1) * 4096 + 2048);
            v0 = *(const short8*)(vsrc + (c + 1) * 64);
            v1 = *(const short8*)(vsrc + (c + 1) * 64 + 32768);
        }
        float4 sv0 = *(const float4*)(sp + c * 64 +  0);
        float4 sv1 = *(const float4*)(sp + c * 64 + 16);
        float4 sv2 = *(const float4*)(sp + c * 64 + 32);
        float4 sv3 = *(const float4*)(sp + c * 64 + 48);
        f32x4 a[4];
#pragma unroll
        for (int tk = 0; tk < 4; tk++) {
            a[tk] = (f32x4){0.f, 0.f, 0.f, 0.f};
            a[tk] = __builtin_amdgcn_mfma_f32_16x16x32_bf16(
                *(const short8*)&sK[hf][tk * 16 + l16][quad * 8], aq0, a[tk], 0, 0, 0);
            a[tk] = __builtin_amdgcn_mfma_f32_16x16x32_bf16(
                *(const short8*)&sK[hf][tk * 16 + l16][32 + quad * 8], aq1, a[tk], 0, 0, 0);
        }
        const float4 svv[4] = {sv0, sv1, sv2, sv3};
#pragma unroll
        for (int tk = 0; tk < 4; tk++) {
            float p0 = __expf(a[tk][0] * fmaf(((const float*)&svv[tk])[0], ratio, 1.0f) - Mhat);
            float p1 = __expf(a[tk][1] * fmaf(((const float*)&svv[tk])[1], ratio, 1.0f) - Mhat);
            float p2 = __expf(a[tk][2] * fmaf(((const float*)&svv[tk])[2], ratio, 1.0f) - Mhat);
            float p3 = __expf(a[tk][3] * fmaf(((const float*)&svv[tk])[3], ratio, 1.0f) - Mhat);
            ls += (p0 + p1) + (p2 + p3);
            s16x4 pk = { f2bf(p0), f2bf(p1), f2bf(p2), f2bf(p3) };
            *(s16x4*)&sP[w][l16][tk * 16 + quad * 4] = pk;
        }
#pragma unroll
        for (int kc = 0; kc < 2; kc++) {
            short8 pa = *(const short8*)&sP[w][l16][kc * 32 + quad * 8];
#pragma unroll
            for (int dt = 0; dt < 4; dt++) {
                short8 vf = *(const short8*)&sV[hf][dt * 16 + l16][kc * 32 + quad * 8];
                O[dt] = __builtin_amdgcn_mfma_f32_16x16x32_bf16(pa, vf, O[dt], 0, 0, 0);
            }
        }
    }
    // ===== combine halves: ls additive, O additive (fixed Mhat) ==========
    ls += __shfl_xor(ls, 16, 64); ls += __shfl_xor(ls, 32, 64);
    if (quad == 0) lsred[hf][t][l16] = ls;
    if (hf == 1) {
#pragma unroll
        for (int dt = 0; dt < 4; dt++)
#pragma unroll
            for (int i = 0; i < 4; i++)
                sO[t][quad * 4 + i][dt * 16 + l16] = O[dt][i];
    }
    __syncthreads();
    if (hf == 0) {
        const float hsum = hm[0] + hm[1] + hm[2] + hm[3] + hm[4] + hm[5] + hm[6] + hm[7];
        const float hscale = hm[h] * 8.0f / hsum;
        float rv[4];
#pragma unroll
        for (int i = 0; i < 4; i++) {
            const int row = quad * 4 + i;
            const float lt = lsred[0][t][row] + lsred[1][t][row];
            rv[i] = hscale / lt;
        }
#pragma unroll
        for (int dt = 0; dt < 4; dt++)
#pragma unroll
            for (int i = 0; i < 4; i++) {
                const float Ot = O[dt][i] + sO[t][quad * 4 + i][dt * 16 + l16];
                o[((size_t)(b * 1024 + q0 + t * 16 + quad * 4 + i)) * 512 + h * 64 + dt * 16 + l16]
                    = f2bf(Ot * rv[i]);
            }
    }
}

// ---------------------------------------------------------------------------
// K3: out = O @ WoT^T + b_out  (M=8192, K=512, N=512). R9 128x64 (frozen).
// ---------------------------------------------------------------------------
__global__ __launch_bounds__(256) void out_gemm(
    const short* __restrict__ A, const short* __restrict__ BT,
    const float* __restrict__ bias, float* __restrict__ out)
{
    __shared__ short sA[128][32];
    __shared__ short sB[64][32];

    const int tid  = threadIdx.x;
    const int wv   = tid >> 6, lane = tid & 63;
    const int quad = lane >> 4, l16 = lane & 15;
    const int m0 = blockIdx.x * 128, n0 = blockIdx.y * 64;

    f32x4 acc[2][4];
#pragma unroll
    for (int i = 0; i < 2; i++)
#pragma unroll
        for (int j = 0; j < 4; j++) acc[i][j] = (f32x4){0.f, 0.f, 0.f, 0.f};

    const short* a_src = A  + (size_t)(m0 + wv * 32 + (lane >> 2)) * 512 + (lane & 3) * 8;
    const short* b_src = BT + (size_t)(n0 + wv * 16 + (lane >> 2)) * 512 + (lane & 3) * 8;
    char* a_dst = (char*)sA + wv * 2048;
    char* b_dst = (char*)sB + wv * 1024;

    for (int ks = 0; ks < 16; ks++) {
        __syncthreads();
        const short* ap = a_src + ks * 32;
        const short* bp = b_src + ks * 32;
        __builtin_amdgcn_global_load_lds((gp1)(ap),            (lp3)(a_dst),        16, 0, 0);
        __builtin_amdgcn_global_load_lds((gp1)(ap + 16 * 512), (lp3)(a_dst + 1024), 16, 0, 0);
        __builtin_amdgcn_global_load_lds((gp1)(bp),            (lp3)(b_dst),        16, 0, 0);
        __syncthreads();

        short8 af[2], bf[4];
#pragma unroll
        for (int f = 0; f < 2; f++)
            af[f] = *(const short8*)&sA[wv * 32 + f * 16 + l16][quad * 8];
#pragma unroll
        for (int f = 0; f < 4; f++)
            bf[f] = *(const short8*)&sB[f * 16 + l16][quad * 8];
#pragma unroll
        for (int fm = 0; fm < 2; fm++)
#pragma unroll
            for (int fn = 0; fn < 4; fn++)
                acc[fm][fn] = __builtin_amdgcn_mfma_f32_16x16x32_bf16(
                    af[fm], bf[fn], acc[fm][fn], 0, 0, 0);
    }

#pragma unroll
    for (int fn = 0; fn < 4; fn++) {
        const int gc = n0 + fn * 16 + l16;
        const float bv = bias[gc];
#pragma unroll
        for (int fm = 0; fm < 2; fm++)
#pragma unroll
            for (int i = 0; i < 4; i++) {
                const int gm = m0 + wv * 32 + fm * 16 + quad * 4 + i;
                out[(size_t)gm * 512 + gc] = acc[fm][fn][i] + bv;
            }
    }
}

// ---------------------------------------------------------------------------
extern "C" void kernel_launch(void* const* d_in, const int* in_sizes, int n_in,
                              void* d_out, int out_size, void* d_ws, size_t ws_size,
                              hipStream_t stream) {
    const float* x    = (const float*)d_in[0];
    const float* spd  = (const float*)d_in[1];
    const float* hm   = (const float*)d_in[2];
    const float* Wqkv = (const float*)d_in[3];
    const float* Wout = (const float*)d_in[4];
    const float* bout = (const float*)d_in[5];
    float* out = (float*)d_out;

    char* ws = (char*)d_ws;
    short* qw  = (short*)(ws);                      // 8 MB  [bh][n][d] bf16 (pre-scaled)
    short* kw  = (short*)(ws + ((size_t)8  << 20)); // 8 MB  [bh][n][d] bf16
    short* vtw = (short*)(ws + ((size_t)16 << 20)); // 8 MB  [bh][d][n] bf16
    short* ow  = (short*)(ws + ((size_t)24 << 20)); // 8 MB  [b][n][h*64+d] bf16
    short* xb  = (short*)(ws + ((size_t)32 << 20)); // 8 MB  x bf16 [8192][512]
    short* wqT = (short*)(ws + ((size_t)40 << 20)); // 1.5MB Wqkv^T bf16 [1536][512]
    short* woT = (short*)(ws + ((size_t)42 << 20)); // 0.5MB Wout^T bf16 [512][512]

    cvt_bf16<<<4096, 256, 0, stream>>>(x, xb, 8192 * 512 / 4);
    tr_w    <<<dim3(8, 24), 256, 0, stream>>>(Wqkv, wqT, 512, 1536);
    tr_w    <<<dim3(8, 8),  256, 0, stream>>>(Wout, woT, 512, 512);

    qkv_gemm<<<dim3(64, 24), 256, 0, stream>>>(xb, wqT, qw, kw, vtw);
    attn_k  <<<dim3(16, 64), 512, 0, stream>>>(qw, kw, vtw, spd, hm, ow);
    out_gemm<<<dim3(64, 8),  256, 0, stream>>>(ow, woT, bout, out);
}

// Round 14
// 224.231 us; speedup vs baseline: 1.1178x; 1.1178x over previous
//
#include <hip/hip_runtime.h>
#include <hip/hip_bf16.h>

typedef __attribute__((ext_vector_type(8))) short short8;
typedef __attribute__((ext_vector_type(4))) short s16x4;
typedef __attribute__((ext_vector_type(4))) float f32x4;

typedef const __attribute__((address_space(1))) unsigned* gp1;
typedef __attribute__((address_space(3))) unsigned* lp3;

__device__ inline short f2bf(float f) {
    union { float f; unsigned u; } v; v.f = f;
    unsigned r = v.u + 0x7fffu + ((v.u >> 16) & 1u);
    return (short)(r >> 16);
}

// ---------------------------------------------------------------------------
// P0: fp32 -> bf16 flat convert (x)
// ---------------------------------------------------------------------------
__global__ __launch_bounds__(256) void cvt_bf16(
    const float* __restrict__ src, short* __restrict__ dst, int n4)
{
    int i = blockIdx.x * 256 + threadIdx.x;
    if (i < n4) {
        float4 v = ((const float4*)src)[i];
        s16x4 o = { f2bf(v.x), f2bf(v.y), f2bf(v.z), f2bf(v.w) };
        ((s16x4*)dst)[i] = o;
    }
}

// ---------------------------------------------------------------------------
// P1: W[K][N] fp32 -> W^T[N][K] bf16 (64x64 LDS tile transpose)
// ---------------------------------------------------------------------------
__global__ __launch_bounds__(256) void tr_w(
    const float* __restrict__ src, short* __restrict__ dst, int K, int N)
{
    __shared__ float t[64][65];
    const int k0 = blockIdx.x * 64, n0 = blockIdx.y * 64;
    const int r = threadIdx.x >> 4, c4 = (threadIdx.x & 15) * 4;
#pragma unroll
    for (int j = 0; j < 4; j++) {
        float4 v = *(const float4*)(src + (size_t)(k0 + r + 16 * j) * N + n0 + c4);
        t[r + 16 * j][c4 + 0] = v.x; t[r + 16 * j][c4 + 1] = v.y;
        t[r + 16 * j][c4 + 2] = v.z; t[r + 16 * j][c4 + 3] = v.w;
    }
    __syncthreads();
#pragma unroll
    for (int j = 0; j < 4; j++) {
        const int n = r + 16 * j;
        s16x4 o = { f2bf(t[c4 + 0][n]), f2bf(t[c4 + 1][n]),
                    f2bf(t[c4 + 2][n]), f2bf(t[c4 + 3][n]) };
        *(s16x4*)(dst + (size_t)(n0 + n) * K + k0 + c4) = o;
    }
}

// ---------------------------------------------------------------------------
// K1: qkv = xb @ WqT^T  (M=8192, K=512, N=1536). R9 128x64 tiles (frozen).
// ---------------------------------------------------------------------------
__global__ __launch_bounds__(256) void qkv_gemm(
    const short* __restrict__ A, const short* __restrict__ BT,
    short* __restrict__ q, short* __restrict__ k, short* __restrict__ vt)
{
    __shared__ short sA[128][32];   // NO padding: global_load_lds needs dense
    __shared__ short sB[64][32];

    const int tid  = threadIdx.x;
    const int wv   = tid >> 6, lane = tid & 63;
    const int quad = lane >> 4, l16 = lane & 15;
    const int m0 = blockIdx.x * 128, n0 = blockIdx.y * 64;

    f32x4 acc[2][4];
#pragma unroll
    for (int i = 0; i < 2; i++)
#pragma unroll
        for (int j = 0; j < 4; j++) acc[i][j] = (f32x4){0.f, 0.f, 0.f, 0.f};

    const short* a_src = A  + (size_t)(m0 + wv * 32 + (lane >> 2)) * 512 + (lane & 3) * 8;
    const short* b_src = BT + (size_t)(n0 + wv * 16 + (lane >> 2)) * 512 + (lane & 3) * 8;
    char* a_dst = (char*)sA + wv * 2048;
    char* b_dst = (char*)sB + wv * 1024;

    for (int ks = 0; ks < 16; ks++) {
        __syncthreads();
        const short* ap = a_src + ks * 32;
        const short* bp = b_src + ks * 32;
        __builtin_amdgcn_global_load_lds((gp1)(ap),            (lp3)(a_dst),        16, 0, 0);
        __builtin_amdgcn_global_load_lds((gp1)(ap + 16 * 512), (lp3)(a_dst + 1024), 16, 0, 0);
        __builtin_amdgcn_global_load_lds((gp1)(bp),            (lp3)(b_dst),        16, 0, 0);
        __syncthreads();

        short8 af[2], bf[4];
#pragma unroll
        for (int f = 0; f < 2; f++)
            af[f] = *(const short8*)&sA[wv * 32 + f * 16 + l16][quad * 8];
#pragma unroll
        for (int f = 0; f < 4; f++)
            bf[f] = *(const short8*)&sB[f * 16 + l16][quad * 8];
#pragma unroll
        for (int fm = 0; fm < 2; fm++)
#pragma unroll
            for (int fn = 0; fn < 4; fn++)
                acc[fm][fn] = __builtin_amdgcn_mfma_f32_16x16x32_bf16(
                    af[fm], bf[fn], acc[fm][fn], 0, 0, 0);
    }

    const int sec = n0 >> 9;   // 0=q 1=k 2=v
#pragma unroll
    for (int fn = 0; fn < 4; fn++) {
        const int gc = n0 + fn * 16 + l16;
        const int cc = gc & 511;
        const int h = cc >> 6, d = cc & 63;
#pragma unroll
        for (int fm = 0; fm < 2; fm++)
#pragma unroll
            for (int i = 0; i < 4; i++) {
                const int gm = m0 + wv * 32 + fm * 16 + quad * 4 + i;
                const int b = gm >> 10, n = gm & 1023;
                const int bh = b * 8 + h;
                if (sec == 0)      q[((size_t)(bh * 1024 + n)) * 64 + d] = f2bf(acc[fm][fn][i] * 0.125f);
                else if (sec == 1) k[((size_t)(bh * 1024 + n)) * 64 + d] = f2bf(acc[fm][fn][i]);
                else               vt[((size_t)(bh * 64 + d)) * 1024 + n] = f2bf(acc[fm][fn][i]);
            }
    }
}

// ---------------------------------------------------------------------------
// K2: attention (R14 = R12 persistent-K + T5 s_setprio around MFMA clusters).
//   R13 refuted TLP theory: 2x waves (key-split) = 22% SLOWER (shared
//   LDS/L2 contention + 4x staging traffic). R12 (102us, 8 waves/CU) is the
//   best structure. R14 adds the one proven-positive attn lever left:
//   s_setprio(1) around MFMA bursts (+4-7% attn, m191) — sweep A is
//   barrier-free (waves at different phases) and sweep B has role-split.
//   Everything else identical to R12. TRIPWIRE: WRITE_SIZE ~8.2MB.
// ---------------------------------------------------------------------------
__global__ __launch_bounds__(512, 2) void attn_k(
    const short* __restrict__ q, const short* __restrict__ kk,
    const short* __restrict__ vt, const float* __restrict__ spd,
    const float* __restrict__ hm, short* __restrict__ o)
{
    __shared__ short sK[65536];        // [1024 keys][64 d] swizzled, 128 KB
    __shared__ short sV[64][72];
    __shared__ short sP[8][16][72];
    __shared__ float sred[8][32];

    const int tid  = threadIdx.x;
    const int wv   = tid >> 6, lane = tid & 63;
    const int quad = lane >> 4, l16 = lane & 15;
    const int qt = blockIdx.x, bh = blockIdx.y;
    const int b = bh >> 3, h = bh & 7;
    const int q0 = qt * 256;

    // Q as B-operand, two 16-row tiles per wave: rows q0+wv*32+{l16, 16+l16}
    const short* qbA = q + ((size_t)bh * 1024 + q0 + wv * 32 + l16) * 64;
    short8 aqA0 = *(const short8*)(qbA + quad * 8);
    short8 aqA1 = *(const short8*)(qbA + 32 + quad * 8);
    const short* qbB = qbA + 16 * 64;
    short8 aqB0 = *(const short8*)(qbB + quad * 8);
    short8 aqB1 = *(const short8*)(qbB + 32 + quad * 8);

    // ---- init: stage ALL K into swizzled LDS (once per block) ----
    {
        const int r0 = tid & 63, w = tid >> 6;
        const short* ks = kk + (size_t)bh * 65536 + (size_t)r0 * 64 + w * 8;
        const int swz = (w * 16) ^ ((r0 & 7) << 4);
#pragma unroll
        for (int it = 0; it < 16; it += 4) {
            short8 t0 = *(const short8*)(ks + (it + 0) * 4096);
            short8 t1 = *(const short8*)(ks + (it + 1) * 4096);
            short8 t2 = *(const short8*)(ks + (it + 2) * 4096);
            short8 t3 = *(const short8*)(ks + (it + 3) * 4096);
            *(short8*)((char*)sK + (r0 + 64 * (it + 0)) * 128 + swz) = t0;
            *(short8*)((char*)sK + (r0 + 64 * (it + 1)) * 128 + swz) = t1;
            *(short8*)((char*)sK + (r0 + 64 * (it + 2)) * 128 + swz) = t2;
            *(short8*)((char*)sK + (r0 + 64 * (it + 3)) * 128 + swz) = t3;
        }
    }
    __syncthreads();

    const int swzr = (l16 & 7) << 4;
    const float* spA = spd + ((size_t)b * 1024 + q0 + wv * 32 + l16) * 1024 + quad * 4;
    const float* spB = spA + (size_t)16 * 1024;

    // ===== sweep A: row norms + max bound — BARRIER-FREE =================
    float dnA = 0.f, pnA = 0.f, mxsA = -1e30f, mxpA = -1e30f;
    float dnB = 0.f, pnB = 0.f, mxsB = -1e30f, mxpB = -1e30f;

    for (int c = 0; c < 16; ++c) {
        short8 kf0[4], kf1[4];
#pragma unroll
        for (int t = 0; t < 4; t++) {
            const int rb = (c * 64 + t * 16 + l16) * 128;
            kf0[t] = *(const short8*)((const char*)sK + rb + ((quad * 16) ^ swzr));
            kf1[t] = *(const short8*)((const char*)sK + rb + ((64 + quad * 16) ^ swzr));
        }
        // ---- tile A ----
        {
            float4 sv0 = *(const float4*)(spA + c * 64 +  0);
            float4 sv1 = *(const float4*)(spA + c * 64 + 16);
            float4 sv2 = *(const float4*)(spA + c * 64 + 32);
            float4 sv3 = *(const float4*)(spA + c * 64 + 48);
            f32x4 a[4];
            __builtin_amdgcn_s_setprio(1);
#pragma unroll
            for (int t = 0; t < 4; t++) {
                a[t] = (f32x4){0.f, 0.f, 0.f, 0.f};
                a[t] = __builtin_amdgcn_mfma_f32_16x16x32_bf16(kf0[t], aqA0, a[t], 0, 0, 0);
                a[t] = __builtin_amdgcn_mfma_f32_16x16x32_bf16(kf1[t], aqA1, a[t], 0, 0, 0);
            }
            __builtin_amdgcn_s_setprio(0);
            const float4 svv[4] = {sv0, sv1, sv2, sv3};
#pragma unroll
            for (int t = 0; t < 4; t++)
#pragma unroll
                for (int i = 0; i < 4; i++) {
                    float s  = a[t][i];
                    float sv = ((const float*)&svv[t])[i];
                    float ps = s * sv;
                    dnA = fmaf(s, s, dnA);
                    pnA = fmaf(ps, ps, pnA);
                    mxsA = fmaxf(mxsA, s);
                    mxpA = fmaxf(mxpA, ps);
                }
        }
        // ---- tile B (reuses kf) ----
        {
            float4 sv0 = *(const float4*)(spB + c * 64 +  0);
            float4 sv1 = *(const float4*)(spB + c * 64 + 16);
            float4 sv2 = *(const float4*)(spB + c * 64 + 32);
            float4 sv3 = *(const float4*)(spB + c * 64 + 48);
            f32x4 a[4];
            __builtin_amdgcn_s_setprio(1);
#pragma unroll
            for (int t = 0; t < 4; t++) {
                a[t] = (f32x4){0.f, 0.f, 0.f, 0.f};
                a[t] = __builtin_amdgcn_mfma_f32_16x16x32_bf16(kf0[t], aqB0, a[t], 0, 0, 0);
                a[t] = __builtin_amdgcn_mfma_f32_16x16x32_bf16(kf1[t], aqB1, a[t], 0, 0, 0);
            }
            __builtin_amdgcn_s_setprio(0);
            const float4 svv[4] = {sv0, sv1, sv2, sv3};
#pragma unroll
            for (int t = 0; t < 4; t++)
#pragma unroll
                for (int i = 0; i < 4; i++) {
                    float s  = a[t][i];
                    float sv = ((const float*)&svv[t])[i];
                    float ps = s * sv;
                    dnB = fmaf(s, s, dnB);
                    pnB = fmaf(ps, ps, pnB);
                    mxsB = fmaxf(mxsB, s);
                    mxpB = fmaxf(mxpB, ps);
                }
        }
    }
    dnA += __shfl_xor(dnA, 16, 64); dnA += __shfl_xor(dnA, 32, 64);
    pnA += __shfl_xor(pnA, 16, 64); pnA += __shfl_xor(pnA, 32, 64);
    dnB += __shfl_xor(dnB, 16, 64); dnB += __shfl_xor(dnB, 32, 64);
    pnB += __shfl_xor(pnB, 16, 64); pnB += __shfl_xor(pnB, 32, 64);
    mxsA = fmaxf(mxsA, __shfl_xor(mxsA, 16, 64)); mxsA = fmaxf(mxsA, __shfl_xor(mxsA, 32, 64));
    mxpA = fmaxf(mxpA, __shfl_xor(mxpA, 16, 64)); mxpA = fmaxf(mxpA, __shfl_xor(mxpA, 32, 64));
    mxsB = fmaxf(mxsB, __shfl_xor(mxsB, 16, 64)); mxsB = fmaxf(mxsB, __shfl_xor(mxsB, 32, 64));
    mxpB = fmaxf(mxpB, __shfl_xor(mxpB, 16, 64)); mxpB = fmaxf(mxpB, __shfl_xor(mxpB, 32, 64));
    const float ratioA = sqrtf(dnA) / fmaxf(sqrtf(pnA), 1e-12f);
    const float ratioB = sqrtf(dnB) / fmaxf(sqrtf(pnB), 1e-12f);
    const float MhatA  = mxsA + ratioA * mxpA;     // >= max_k l (tile A rows)
    const float MhatB  = mxsB + ratioB * mxpB;

    // ===== sweep B: V-only staging; QK from resident K; exp; PV ==========
    float lsA = 0.f, lsB = 0.f;
    f32x4 OA[4], OB[4];
#pragma unroll
    for (int dt = 0; dt < 4; dt++) {
        OA[dt] = (f32x4){0.f, 0.f, 0.f, 0.f};
        OB[dt] = (f32x4){0.f, 0.f, 0.f, 0.f};
    }

    const int rv = tid & 63, cv = (tid >> 6) * 8;
    const short* vsrc = vt + (size_t)bh * 65536 + (size_t)rv * 1024 + cv;
    short8 v0 = *(const short8*)(vsrc);

    for (int c = 0; c < 16; ++c) {
        __syncthreads();                   // prior PV reads of sV complete
        *(short8*)&sV[rv][cv] = v0;
        __syncthreads();
        if (c < 15) v0 = *(const short8*)(vsrc + (c + 1) * 64);

        short8 kf0[4], kf1[4];
#pragma unroll
        for (int t = 0; t < 4; t++) {
            const int rb = (c * 64 + t * 16 + l16) * 128;
            kf0[t] = *(const short8*)((const char*)sK + rb + ((quad * 16) ^ swzr));
            kf1[t] = *(const short8*)((const char*)sK + rb + ((64 + quad * 16) ^ swzr));
        }
        // ---- tile A: QK -> p -> sP -> PV ----
        {
            float4 sv0 = *(const float4*)(spA + c * 64 +  0);
            float4 sv1 = *(const float4*)(spA + c * 64 + 16);
            float4 sv2 = *(const float4*)(spA + c * 64 + 32);
            float4 sv3 = *(const float4*)(spA + c * 64 + 48);
            f32x4 a[4];
            __builtin_amdgcn_s_setprio(1);
#pragma unroll
            for (int t = 0; t < 4; t++) {
                a[t] = (f32x4){0.f, 0.f, 0.f, 0.f};
                a[t] = __builtin_amdgcn_mfma_f32_16x16x32_bf16(kf0[t], aqA0, a[t], 0, 0, 0);
                a[t] = __builtin_amdgcn_mfma_f32_16x16x32_bf16(kf1[t], aqA1, a[t], 0, 0, 0);
            }
            __builtin_amdgcn_s_setprio(0);
            const float4 svv[4] = {sv0, sv1, sv2, sv3};
#pragma unroll
            for (int t = 0; t < 4; t++) {
                float p0 = __expf(a[t][0] * fmaf(((const float*)&svv[t])[0], ratioA, 1.0f) - MhatA);
                float p1 = __expf(a[t][1] * fmaf(((const float*)&svv[t])[1], ratioA, 1.0f) - MhatA);
                float p2 = __expf(a[t][2] * fmaf(((const float*)&svv[t])[2], ratioA, 1.0f) - MhatA);
                float p3 = __expf(a[t][3] * fmaf(((const float*)&svv[t])[3], ratioA, 1.0f) - MhatA);
                lsA += (p0 + p1) + (p2 + p3);
                s16x4 pk = { f2bf(p0), f2bf(p1), f2bf(p2), f2bf(p3) };
                *(s16x4*)&sP[wv][l16][t * 16 + quad * 4] = pk;
            }
            __builtin_amdgcn_s_setprio(1);
#pragma unroll
            for (int kc = 0; kc < 2; kc++) {
                short8 pa = *(const short8*)&sP[wv][l16][kc * 32 + quad * 8];
#pragma unroll
                for (int dt = 0; dt < 4; dt++) {
                    short8 vf = *(const short8*)&sV[dt * 16 + l16][kc * 32 + quad * 8];
                    OA[dt] = __builtin_amdgcn_mfma_f32_16x16x32_bf16(pa, vf, OA[dt], 0, 0, 0);
                }
            }
            __builtin_amdgcn_s_setprio(0);
        }
        // ---- tile B: QK -> p -> sP -> PV (same sP rows, same-wave order) --
        {
            float4 sv0 = *(const float4*)(spB + c * 64 +  0);
            float4 sv1 = *(const float4*)(spB + c * 64 + 16);
            float4 sv2 = *(const float4*)(spB + c * 64 + 32);
            float4 sv3 = *(const float4*)(spB + c * 64 + 48);
            f32x4 a[4];
            __builtin_amdgcn_s_setprio(1);
#pragma unroll
            for (int t = 0; t < 4; t++) {
                a[t] = (f32x4){0.f, 0.f, 0.f, 0.f};
                a[t] = __builtin_amdgcn_mfma_f32_16x16x32_bf16(kf0[t], aqB0, a[t], 0, 0, 0);
                a[t] = __builtin_amdgcn_mfma_f32_16x16x32_bf16(kf1[t], aqB1, a[t], 0, 0, 0);
            }
            __builtin_amdgcn_s_setprio(0);
            const float4 svv[4] = {sv0, sv1, sv2, sv3};
#pragma unroll
            for (int t = 0; t < 4; t++) {
                float p0 = __expf(a[t][0] * fmaf(((const float*)&svv[t])[0], ratioB, 1.0f) - MhatB);
                float p1 = __expf(a[t][1] * fmaf(((const float*)&svv[t])[1], ratioB, 1.0f) - MhatB);
                float p2 = __expf(a[t][2] * fmaf(((const float*)&svv[t])[2], ratioB, 1.0f) - MhatB);
                float p3 = __expf(a[t][3] * fmaf(((const float*)&svv[t])[3], ratioB, 1.0f) - MhatB);
                lsB += (p0 + p1) + (p2 + p3);
                s16x4 pk = { f2bf(p0), f2bf(p1), f2bf(p2), f2bf(p3) };
                *(s16x4*)&sP[wv][l16][t * 16 + quad * 4] = pk;
            }
            __builtin_amdgcn_s_setprio(1);
#pragma unroll
            for (int kc = 0; kc < 2; kc++) {
                short8 pa = *(const short8*)&sP[wv][l16][kc * 32 + quad * 8];
#pragma unroll
                for (int dt = 0; dt < 4; dt++) {
                    short8 vf = *(const short8*)&sV[dt * 16 + l16][kc * 32 + quad * 8];
                    OB[dt] = __builtin_amdgcn_mfma_f32_16x16x32_bf16(pa, vf, OB[dt], 0, 0, 0);
                }
            }
            __builtin_amdgcn_s_setprio(0);
        }
    }
    // final normalization (per tile, row l16 domain)
    lsA += __shfl_xor(lsA, 16, 64); lsA += __shfl_xor(lsA, 32, 64);
    lsB += __shfl_xor(lsB, 16, 64); lsB += __shfl_xor(lsB, 32, 64);
    const float hsum = hm[0] + hm[1] + hm[2] + hm[3] + hm[4] + hm[5] + hm[6] + hm[7];
    const float hscale = hm[h] * 8.0f / hsum;
    const float rinvA = hscale / lsA;
    const float rinvB = hscale / lsB;
    if (quad == 0) { sred[wv][l16] = rinvA; sred[wv][16 + l16] = rinvB; }
    __syncthreads();
    float rvA[4], rvB[4];
#pragma unroll
    for (int i = 0; i < 4; i++) {
        rvA[i] = sred[wv][quad * 4 + i];
        rvB[i] = sred[wv][16 + quad * 4 + i];
    }
#pragma unroll
    for (int dt = 0; dt < 4; dt++)
#pragma unroll
        for (int i = 0; i < 4; i++) {
            o[((size_t)(b * 1024 + q0 + wv * 32 + quad * 4 + i)) * 512 + h * 64 + dt * 16 + l16]
                = f2bf(OA[dt][i] * rvA[i]);
            o[((size_t)(b * 1024 + q0 + wv * 32 + 16 + quad * 4 + i)) * 512 + h * 64 + dt * 16 + l16]
                = f2bf(OB[dt][i] * rvB[i]);
        }
}

// ---------------------------------------------------------------------------
// K3: out = O @ WoT^T + b_out  (M=8192, K=512, N=512). R9 128x64 (frozen).
// ---------------------------------------------------------------------------
__global__ __launch_bounds__(256) void out_gemm(
    const short* __restrict__ A, const short* __restrict__ BT,
    const float* __restrict__ bias, float* __restrict__ out)
{
    __shared__ short sA[128][32];
    __shared__ short sB[64][32];

    const int tid  = threadIdx.x;
    const int wv   = tid >> 6, lane = tid & 63;
    const int quad = lane >> 4, l16 = lane & 15;
    const int m0 = blockIdx.x * 128, n0 = blockIdx.y * 64;

    f32x4 acc[2][4];
#pragma unroll
    for (int i = 0; i < 2; i++)
#pragma unroll
        for (int j = 0; j < 4; j++) acc[i][j] = (f32x4){0.f, 0.f, 0.f, 0.f};

    const short* a_src = A  + (size_t)(m0 + wv * 32 + (lane >> 2)) * 512 + (lane & 3) * 8;
    const short* b_src = BT + (size_t)(n0 + wv * 16 + (lane >> 2)) * 512 + (lane & 3) * 8;
    char* a_dst = (char*)sA + wv * 2048;
    char* b_dst = (char*)sB + wv * 1024;

    for (int ks = 0; ks < 16; ks++) {
        __syncthreads();
        const short* ap = a_src + ks * 32;
        const short* bp = b_src + ks * 32;
        __builtin_amdgcn_global_load_lds((gp1)(ap),            (lp3)(a_dst),        16, 0, 0);
        __builtin_amdgcn_global_load_lds((gp1)(ap + 16 * 512), (lp3)(a_dst + 1024), 16, 0, 0);
        __builtin_amdgcn_global_load_lds((gp1)(bp),            (lp3)(b_dst),        16, 0, 0);
        __syncthreads();

        short8 af[2], bf[4];
#pragma unroll
        for (int f = 0; f < 2; f++)
            af[f] = *(const short8*)&sA[wv * 32 + f * 16 + l16][quad * 8];
#pragma unroll
        for (int f = 0; f < 4; f++)
            bf[f] = *(const short8*)&sB[f * 16 + l16][quad * 8];
#pragma unroll
        for (int fm = 0; fm < 2; fm++)
#pragma unroll
            for (int fn = 0; fn < 4; fn++)
                acc[fm][fn] = __builtin_amdgcn_mfma_f32_16x16x32_bf16(
                    af[fm], bf[fn], acc[fm][fn], 0, 0, 0);
    }

#pragma unroll
    for (int fn = 0; fn < 4; fn++) {
        const int gc = n0 + fn * 16 + l16;
        const float bv = bias[gc];
#pragma unroll
        for (int fm = 0; fm < 2; fm++)
#pragma unroll
            for (int i = 0; i < 4; i++) {
                const int gm = m0 + wv * 32 + fm * 16 + quad * 4 + i;
                out[(size_t)gm * 512 + gc] = acc[fm][fn][i] + bv;
            }
    }
}

// ---------------------------------------------------------------------------
extern "C" void kernel_launch(void* const* d_in, const int* in_sizes, int n_in,
                              void* d_out, int out_size, void* d_ws, size_t ws_size,
                              hipStream_t stream) {
    const float* x    = (const float*)d_in[0];
    const float* spd  = (const float*)d_in[1];
    const float* hm   = (const float*)d_in[2];
    const float* Wqkv = (const float*)d_in[3];
    const float* Wout = (const float*)d_in[4];
    const float* bout = (const float*)d_in[5];
    float* out = (float*)d_out;

    char* ws = (char*)d_ws;
    short* qw  = (short*)(ws);                      // 8 MB  [bh][n][d] bf16 (pre-scaled)
    short* kw  = (short*)(ws + ((size_t)8  << 20)); // 8 MB  [bh][n][d] bf16
    short* vtw = (short*)(ws + ((size_t)16 << 20)); // 8 MB  [bh][d][n] bf16
    short* ow  = (short*)(ws + ((size_t)24 << 20)); // 8 MB  [b][n][h*64+d] bf16
    short* xb  = (short*)(ws + ((size_t)32 << 20)); // 8 MB  x bf16 [8192][512]
    short* wqT = (short*)(ws + ((size_t)40 << 20)); // 1.5MB Wqkv^T bf16 [1536][512]
    short* woT = (short*)(ws + ((size_t)42 << 20)); // 0.5MB Wout^T bf16 [512][512]

    cvt_bf16<<<4096, 256, 0, stream>>>(x, xb, 8192 * 512 / 4);
    tr_w    <<<dim3(8, 24), 256, 0, stream>>>(Wqkv, wqT, 512, 1536);
    tr_w    <<<dim3(8, 8),  256, 0, stream>>>(Wout, woT, 512, 512);

    qkv_gemm<<<dim3(64, 24), 256, 0, stream>>>(xb, wqT, qw, kw, vtw);
    attn_k  <<<dim3(4, 64),  512, 0, stream>>>(qw, kw, vtw, spd, hm, ow);
    out_gemm<<<dim3(64, 8),  256, 0, stream>>>(ow, woT, bout, out);
}